// Round 4
// baseline (990.261 us; speedup 1.0000x reference)
//
#include <hip/hip_runtime.h>
#include <math.h>

typedef unsigned short u16;
typedef unsigned int   u32;
typedef __attribute__((ext_vector_type(8))) short short8;
typedef __attribute__((ext_vector_type(4))) float f32x4;

#define NPTS 4096
#define NB   16
#define FLT_BIG 3.402823466e38f

// ---- workspace layout (float offsets) ----
static const size_t OFF_Y1  = 0;                          // 16*256*4096
static const size_t OFF_Y2  = 16777216;                   // 16*512*4096
static const size_t OFF_W1I = 50331648;                   // 516096 u16
static const size_t OFF_W2I = 50589696;                   // 393216 u16
static const size_t OFF_W3I = 50786304;                   // 1572864 u16
static const size_t OFF_PS  = 51572736;
static const size_t OFF_PQ  = 52621312;
static const size_t OFF_PMX = 53669888;
static const size_t OFF_PMN = 54718464;
static const size_t OFF_AC  = 55767040;
static const size_t OFF_SHC = 55768064;
// total ~223 MB

// XOR swizzle: spread 64B-stride rows across banks; moves 16B granules within 128B windows.
__device__ __forceinline__ u32 swz(u32 b) { return b ^ ((b >> 2) & 0x70u); }

__device__ __forceinline__ u16 f2bf(float x) {
    u32 u = __float_as_uint(x);
    u32 r = (u + 0x7FFFu + ((u >> 16) & 1u)) >> 16;
    return (u16)r;
}
__device__ __forceinline__ float bf2f(u16 h) {
    return __uint_as_float(((u32)h) << 16);
}
__device__ __forceinline__ void gload_lds16(const void* g, void* l) {
    __builtin_amdgcn_global_load_lds(
        (const __attribute__((address_space(1))) u32*)g,
        (__attribute__((address_space(3))) u32*)l, 16, 0, 0);
}

// ---- fused W prep: split into 3-plane swizzled LDS-image  img[mt*KT+kt][plane][swz(m*64+k*2)] ----
__global__ __launch_bounds__(256) void prep_all(const float* __restrict__ W1,
                                                const float* __restrict__ W2,
                                                const float* __restrict__ W3,
                                                u16* __restrict__ w1i,
                                                u16* __restrict__ w2i,
                                                u16* __restrict__ w3i) {
    const int bx = blockIdx.x;
    const float* W; u16* img; int Kact, KT, mt, kt;
    if (bx < 42)      { W = W1; img = w1i; Kact = 643; KT = 21; mt = bx / 21;        kt = bx % 21; }
    else if (bx < 74) { W = W2; img = w2i; Kact = 256; KT = 8;  mt = (bx - 42) / 8;  kt = (bx - 42) % 8; }
    else              { W = W3; img = w3i; Kact = 512; KT = 16; mt = (bx - 74) / 16; kt = (bx - 74) % 16; }

    const int t = threadIdx.x;
    const int ml = t >> 1, kl0 = (t & 1) * 16;
    const int m = mt * 128 + ml;
    u16* tb = img + (size_t)(mt * KT + kt) * 12288;
#pragma unroll
    for (int j = 0; j < 16; ++j) {
        const int kk = kl0 + j;
        const int k = kt * 32 + kk;
        const float w = (k < Kact) ? W[(size_t)m * Kact + k] : 0.f;
        const u16 h = f2bf(w);
        const float r1 = w - bf2f(h);
        const u16 md = f2bf(r1);
        const float r2 = r1 - bf2f(md);
        const u16 lo = f2bf(r2);
        const u32 so = swz((u32)(ml * 64 + kk * 2)) >> 1;   // u16 index within plane
        tb[so]        = h;
        tb[4096 + so] = md;
        tb[8192 + so] = lo;
    }
}

// ---- fused split-bf16 MFMA GEMM (6 plane-products) ----
template<bool BN_IN, bool STORE, bool MAXMIN>
__global__ __launch_bounds__(256)
void gemm6(const u16* __restrict__ Wimg, int KT, int Kact, int M_,
           const float* __restrict__ bias,
           const float* __restrict__ X,            // [NB][Kact][4096] fp32
           const float* __restrict__ a_in, const float* __restrict__ sh_in,
           float* __restrict__ Y,
           float* __restrict__ psum, float* __restrict__ psq,
           float* __restrict__ pmax, float* __restrict__ pmin, int NT)
{
    __shared__ __align__(16) u16 AsU[3 * 128 * 32];   // [3][swz(m*64+k*2)]
    __shared__ __align__(16) u16 BsU[3 * 128 * 32];   // [3][swz(n*64+k*2)]

    const int tid  = threadIdx.x;
    const int lane = tid & 63, wid = tid >> 6;
    const int l15 = lane & 15, l4 = lane >> 4;
    const int wm = wid >> 1, wn = wid & 1;
    const int nt = blockIdx.x, mtb = blockIdx.y, b = blockIdx.z;
    const int m0 = mtb * 128, n0 = nt * 128;

    // B staging mapping: thread owns k in [kot*8, kot*8+8), n in {2*npair, 2*npair+1}
    const int kot   = tid & 3;
    const int npair = tid >> 2;

    // loop-invariant swizzled LDS offsets (bytes, within-plane)
    u32 aoff[4], boff[4];
#pragma unroll
    for (int f = 0; f < 4; ++f) {
        aoff[f] = swz((u32)((wm * 64 + f * 16 + l15) * 64 + l4 * 16));
        boff[f] = swz((u32)((wn * 64 + f * 16 + l15) * 64 + l4 * 16));
    }
    u32 woff[2];
#pragma unroll
    for (int e = 0; e < 2; ++e)
        woff[e] = swz((u32)((npair * 2 + e) * 64 + kot * 16));

    f32x4 acc[4][4];
#pragma unroll
    for (int i = 0; i < 4; ++i)
#pragma unroll
        for (int j = 0; j < 4; ++j) acc[i][j] = (f32x4){0.f, 0.f, 0.f, 0.f};

    for (int kt = 0; kt < KT; ++kt) {
        const int kb = kt * 32 + kot * 8;
        // ---- stage A (3 planes, 24KB) via global_load_lds (source pre-swizzled) ----
        {
            const u16* gb = Wimg + (size_t)(mtb * KT + kt) * 12288;
#pragma unroll
            for (int i = 0; i < 6; ++i) {
                const u16* gsrc = gb + i * 2048 + wid * 512 + lane * 8;
                u16* ldst = AsU + i * 2048 + wid * 512;     // wave-uniform; HW adds lane*16B
                gload_lds16(gsrc, ldst);
            }
        }
        // ---- stage B: 8 k-rows x 2 n, BN+ReLU, round-half-up 3-plane split, packed b128 writes ----
        {
            float2 xv[8];
            const float* xb = X + ((size_t)b * Kact + kb) * NPTS + n0 + npair * 2;
#pragma unroll
            for (int j = 0; j < 8; ++j) {
                const int k = kb + j;
                float2 v = {0.f, 0.f};
                if (k < Kact) {
                    v = *(const float2*)(xb + (size_t)j * NPTS);
                    if (BN_IN) {
                        const float ak = a_in[k], sk = sh_in[k];
                        v.x = fmaxf(fmaf(ak, v.x, sk), 0.f);
                        v.y = fmaxf(fmaf(ak, v.y, sk), 0.f);
                    }
                }
                xv[j] = v;
            }
#pragma unroll
            for (int e = 0; e < 2; ++e) {
                u32 hj[8], mj[8], lj[8];
#pragma unroll
                for (int j = 0; j < 8; ++j) {
                    const float x = e ? xv[j].y : xv[j].x;
                    const u32 u  = __float_as_uint(x);
                    const u32 uh = u + 0x8000u;
                    const float r1 = x - __uint_as_float(uh & 0xFFFF0000u);
                    const u32 u1 = __float_as_uint(r1);
                    const u32 um = u1 + 0x8000u;
                    const float r2 = r1 - __uint_as_float(um & 0xFFFF0000u);
                    hj[j] = uh;
                    mj[j] = um;
                    lj[j] = __float_as_uint(r2) + 0x8000u;
                }
                uint4 wh, wm_, wl;
                wh.x = __builtin_amdgcn_perm(hj[1], hj[0], 0x07060302u);
                wh.y = __builtin_amdgcn_perm(hj[3], hj[2], 0x07060302u);
                wh.z = __builtin_amdgcn_perm(hj[5], hj[4], 0x07060302u);
                wh.w = __builtin_amdgcn_perm(hj[7], hj[6], 0x07060302u);
                wm_.x = __builtin_amdgcn_perm(mj[1], mj[0], 0x07060302u);
                wm_.y = __builtin_amdgcn_perm(mj[3], mj[2], 0x07060302u);
                wm_.z = __builtin_amdgcn_perm(mj[5], mj[4], 0x07060302u);
                wm_.w = __builtin_amdgcn_perm(mj[7], mj[6], 0x07060302u);
                wl.x = __builtin_amdgcn_perm(lj[1], lj[0], 0x07060302u);
                wl.y = __builtin_amdgcn_perm(lj[3], lj[2], 0x07060302u);
                wl.z = __builtin_amdgcn_perm(lj[5], lj[4], 0x07060302u);
                wl.w = __builtin_amdgcn_perm(lj[7], lj[6], 0x07060302u);
                char* bp = (char*)BsU + woff[e];
                *(uint4*)(bp)         = wh;
                *(uint4*)(bp + 8192)  = wm_;
                *(uint4*)(bp + 16384) = wl;
            }
        }
        __syncthreads();

        // ---- compute: cache A-frags (3 planes x 4 mf), stream B-frags ----
        short8 af[3][4];
#pragma unroll
        for (int p = 0; p < 3; ++p)
#pragma unroll
            for (int mf = 0; mf < 4; ++mf)
                af[p][mf] = *(const short8*)((const char*)AsU + p * 8192 + aoff[mf]);

#pragma unroll
        for (int pb = 0; pb < 3; ++pb) {
            const int npa = (pb == 0) ? 3 : ((pb == 1) ? 2 : 1);
#pragma unroll
            for (int nf = 0; nf < 4; ++nf) {
                const short8 bfv = *(const short8*)((const char*)BsU + pb * 8192 + boff[nf]);
#pragma unroll
                for (int pa = 0; pa < 3; ++pa) {
                    if (pa < npa) {
#pragma unroll
                        for (int mf = 0; mf < 4; ++mf)
                            acc[mf][nf] = __builtin_amdgcn_mfma_f32_16x16x32_bf16(
                                af[pa][mf], bfv, acc[mf][nf], 0, 0, 0);
                    }
                }
            }
        }
        __syncthreads();
    }

    // ---- epilogue: bias, stats partials, optional store / max-min partials ----
#pragma unroll
    for (int mf = 0; mf < 4; ++mf) {
#pragma unroll
        for (int r = 0; r < 4; ++r) {
            const int m = m0 + wm * 64 + mf * 16 + l4 * 4 + r;
            const float bvv = bias[m];
            float vs[4];
            float rs = 0.f, rq = 0.f;
#pragma unroll
            for (int nf = 0; nf < 4; ++nf) {
                const float v = acc[mf][nf][r] + bvv;
                vs[nf] = v; rs += v; rq = fmaf(v, v, rq);
            }
            float mx = 0.f, mn = 0.f;
            if (MAXMIN) {
                mx = fmaxf(fmaxf(vs[0], vs[1]), fmaxf(vs[2], vs[3]));
                mn = fminf(fminf(vs[0], vs[1]), fminf(vs[2], vs[3]));
            }
            if (STORE) {
#pragma unroll
                for (int nf = 0; nf < 4; ++nf)
                    Y[((size_t)b * M_ + m) * NPTS + n0 + wn * 64 + nf * 16 + l15] = vs[nf];
            }
#pragma unroll
            for (int s = 1; s < 16; s <<= 1) {
                rs += __shfl_xor(rs, s);
                rq += __shfl_xor(rq, s);
                if (MAXMIN) {
                    mx = fmaxf(mx, __shfl_xor(mx, s));
                    mn = fminf(mn, __shfl_xor(mn, s));
                }
            }
            if (l15 == 0) {
                const int slot = (b * NT + nt) * 2 + wn;
                psum[(size_t)slot * M_ + m] = rs;
                psq[(size_t)slot * M_ + m]  = rq;
                if (MAXMIN) {
                    pmax[((size_t)b * M_ + m) * 64 + nt * 2 + wn] = mx;
                    pmin[((size_t)b * M_ + m) * 64 + nt * 2 + wn] = mn;
                }
            }
        }
    }
}

// ---- per-channel stats (1024 slots) -> BN scale/shift ----
__global__ __launch_bounds__(256) void stats_k(const float* __restrict__ psum, const float* __restrict__ psq,
                                               int M_,
                                               const float* __restrict__ g, const float* __restrict__ be,
                                               float* __restrict__ a_out, float* __restrict__ sh_out)
{
    __shared__ double ds[4][64];
    __shared__ double dq[4][64];
    const int mloc = threadIdx.x & 63, q = threadIdx.x >> 6;
    const int m = blockIdx.x * 64 + mloc;
    double s = 0.0, sq = 0.0;
    for (int sl = q * 256; sl < (q + 1) * 256; ++sl) {
        s  += (double)psum[(size_t)sl * M_ + m];
        sq += (double)psq[(size_t)sl * M_ + m];
    }
    ds[q][mloc] = s; dq[q][mloc] = sq;
    __syncthreads();
    if (threadIdx.x < 64) {
        const double S = ds[0][mloc] + ds[1][mloc] + ds[2][mloc] + ds[3][mloc];
        const double Q = dq[0][mloc] + dq[1][mloc] + dq[2][mloc] + dq[3][mloc];
        const double cnt = (double)NB * (double)NPTS;
        double mean = S / cnt;
        double var  = Q / cnt - mean * mean;
        if (var < 0.0) var = 0.0;
        const double a = (double)g[m] / sqrt(var + 1e-5);
        a_out[m]  = (float)a;
        sh_out[m] = (float)((double)be[m] - a * mean);
    }
}

// ---- final: L3 stats (fused), pool-select, BN-apply+ReLU, BN1d over batch ----
__global__ __launch_bounds__(256) void final_k(const float* __restrict__ psum, const float* __restrict__ psq,
                                               const float* __restrict__ g3, const float* __restrict__ be3,
                                               const float* __restrict__ pmax, const float* __restrict__ pmin,
                                               const float* __restrict__ g4, const float* __restrict__ be4,
                                               float* __restrict__ out)
{
    const int c = blockIdx.x * 256 + threadIdx.x;
    if (c >= 1024) return;
    // L3 channel stats over 1024 slots (coalesced: c contiguous across lanes)
    double S = 0.0, Q = 0.0;
    for (int sl = 0; sl < 1024; ++sl) {
        S += (double)psum[(size_t)sl * 1024 + c];
        Q += (double)psq[(size_t)sl * 1024 + c];
    }
    const double cnt = (double)NB * (double)NPTS;
    double mean3 = S / cnt;
    double var3  = Q / cnt - mean3 * mean3;
    if (var3 < 0.0) var3 = 0.0;
    const double a3 = (double)g3[c] / sqrt(var3 + 1e-5);
    const float a = (float)a3;
    const float sh = (float)((double)be3[c] - a3 * mean3);

    float h[NB];
    float s = 0.f;
    for (int b = 0; b < NB; ++b) {
        float mxv = -FLT_BIG, mnv = FLT_BIG;
        const float* pxr = pmax + ((size_t)b * 1024 + c) * 64;
        const float* pnr = pmin + ((size_t)b * 1024 + c) * 64;
        for (int q = 0; q < 64; ++q) {
            mxv = fmaxf(mxv, pxr[q]);
            mnv = fminf(mnv, pnr[q]);
        }
        const float v = (a >= 0.f) ? fmaf(a, mxv, sh) : fmaf(a, mnv, sh);
        h[b] = fmaxf(v, 0.f);
        s += h[b];
    }
    const float mean = s * (1.f / NB);
    float var = 0.f;
    for (int b = 0; b < NB; ++b) { const float d = h[b] - mean; var = fmaf(d, d, var); }
    var *= (1.f / NB);
    const double ai = (double)g4[c] / sqrt((double)var + 1e-5);
    for (int b = 0; b < NB; ++b)
        out[b * 1024 + c] = (float)(ai * ((double)h[b] - (double)mean) + (double)be4[c]);
}

extern "C" void kernel_launch(void* const* d_in, const int* in_sizes, int n_in,
                              void* d_out, int out_size, void* d_ws, size_t ws_size,
                              hipStream_t stream) {
    const float* xyz = (const float*)d_in[0];
    const float* W1  = (const float*)d_in[1];
    const float* b1  = (const float*)d_in[2];
    const float* g1  = (const float*)d_in[3];
    const float* be1 = (const float*)d_in[4];
    const float* W2  = (const float*)d_in[5];
    const float* b2  = (const float*)d_in[6];
    const float* g2  = (const float*)d_in[7];
    const float* be2 = (const float*)d_in[8];
    const float* W3  = (const float*)d_in[9];
    const float* b3  = (const float*)d_in[10];
    const float* g3  = (const float*)d_in[11];
    const float* be3 = (const float*)d_in[12];
    const float* g4  = (const float*)d_in[13];
    const float* be4 = (const float*)d_in[14];

    float* ws = (float*)d_ws;
    float* y1  = ws + OFF_Y1;
    float* y2  = ws + OFF_Y2;
    u16*   w1i = (u16*)(ws + OFF_W1I);
    u16*   w2i = (u16*)(ws + OFF_W2I);
    u16*   w3i = (u16*)(ws + OFF_W3I);
    float* ps  = ws + OFF_PS;
    float* pq  = ws + OFF_PQ;
    float* pmx = ws + OFF_PMX;
    float* pmn = ws + OFF_PMN;
    float* ac  = ws + OFF_AC;
    float* shc = ws + OFF_SHC;
    float* out = (float*)d_out;

    // W-plane swizzled images: L1 42 tiles, L2 32, L3 128
    prep_all<<<202, 256, 0, stream>>>(W1, W2, W3, w1i, w2i, w3i);

    // L1: y1 = W1 @ xyz + b1 (store + stats)
    gemm6<false, true, false><<<dim3(32, 2, 16), 256, 0, stream>>>(
        w1i, 21, 643, 256, b1, xyz, nullptr, nullptr,
        y1, ps, pq, nullptr, nullptr, 32);
    stats_k<<<4, 256, 0, stream>>>(ps, pq, 256, g1, be1, ac, shc);

    // L2: y2 = W2 @ relu(bn(y1)) + b2 (store + stats)
    gemm6<true, true, false><<<dim3(32, 4, 16), 256, 0, stream>>>(
        w2i, 8, 256, 512, b2, y1, ac, shc,
        y2, ps, pq, nullptr, nullptr, 32);
    stats_k<<<8, 256, 0, stream>>>(ps, pq, 512, g2, be2, ac, shc);

    // L3: stats + per-(b,m) max/min partials (no store)
    gemm6<true, false, true><<<dim3(32, 8, 16), 256, 0, stream>>>(
        w3i, 16, 512, 1024, b3, y2, ac, shc,
        nullptr, ps, pq, pmx, pmn, 32);

    // fused L3-stats + pool-select + final BN1d
    final_k<<<4, 256, 0, stream>>>(ps, pq, g3, be3, pmx, pmn, g4, be4, out);
}

// Round 5
// 690.654 us; speedup vs baseline: 1.4338x; 1.4338x over previous
//
#include <hip/hip_runtime.h>
#include <math.h>

typedef unsigned short u16;
typedef unsigned int   u32;
typedef __attribute__((ext_vector_type(8))) short short8;
typedef __attribute__((ext_vector_type(4))) float f32x4;

#define NPTS 4096
#define NB   16
#define FLT_BIG 3.402823466e38f

// ---- workspace layout (float offsets), total ~221 MB ----
static const size_t OFF_Y1  = 0;          // 16,777,216 f
static const size_t OFF_Y2  = 16777216;   // 33,554,432 f
static const size_t OFF_W1I = 50331648;   // 344064 u16 -> 172032 f
static const size_t OFF_W2I = 50503680;   // 262144 u16 -> 131072 f
static const size_t OFF_W3I = 50634752;   // 1048576 u16 -> 524288 f
static const size_t OFF_PS  = 51159040;   // 1,048,576
static const size_t OFF_PQ  = 52207616;   // 1,048,576
static const size_t OFF_PMX = 53256192;   // 1,048,576
static const size_t OFF_PMN = 54304768;   // 1,048,576
static const size_t OFF_AC  = 55353344;   // 1024
static const size_t OFF_SHC = 55354368;   // 1024
static const size_t OFF_ASH = 55355392;   // 2048 (float2[1024])

__device__ __forceinline__ void gload_lds16(const void* g, void* l) {
    __builtin_amdgcn_global_load_lds(
        (const __attribute__((address_space(1))) u32*)g,
        (__attribute__((address_space(3))) u32*)l, 16, 0, 0);
}
__device__ __forceinline__ u32 pk(u32 a, u32 b) {   // [b.hi16 | a.hi16] -> u16 pair (a first)
    return __builtin_amdgcn_perm(b, a, 0x07060302u);
}

// ---- W prep: 2-plane (hi,mid) image in GEMM-ready order ----
// per (chunk,kt) tile of 16384 u16: [plane 2][kot 4][m 256][8k]
__global__ __launch_bounds__(256) void prep_w(const float* __restrict__ W1,
                                              const float* __restrict__ W2,
                                              const float* __restrict__ W3,
                                              u16* __restrict__ w1i,
                                              u16* __restrict__ w2i,
                                              u16* __restrict__ w3i) {
    const int bx = blockIdx.x;
    const float* W; u16* img; int Kact, KT, mc, kt;
    if (bx < 21)      { W = W1; img = w1i; Kact = 643; KT = 21; mc = 0;              kt = bx; }
    else if (bx < 37) { W = W2; img = w2i; Kact = 256; KT = 8;  mc = (bx - 21) >> 3; kt = (bx - 21) & 7; }
    else              { W = W3; img = w3i; Kact = 512; KT = 16; mc = (bx - 37) >> 4; kt = (bx - 37) & 15; }

    u16* tb = img + ((size_t)(mc * KT + kt) << 14);
    for (int it = 0; it < 4; ++it) {
        const int item = it * 256 + threadIdx.x;
        const int m = item & 255, kot = item >> 8;
        const int k0 = kt * 32 + kot * 8;
        const float* wr = W + (size_t)(mc * 256 + m) * Kact;
        u32 hh[8], mm[8];
#pragma unroll
        for (int j = 0; j < 8; ++j) {
            const int k = k0 + j;
            const float x = (k < Kact) ? wr[k] : 0.f;
            const u32 u = __float_as_uint(x);
            const u32 uh = u + 0x8000u;
            const float r1 = x - __uint_as_float(uh & 0xFFFF0000u);
            hh[j] = uh;
            mm[j] = __float_as_uint(r1) + 0x8000u;
        }
        uint4 wh, wmv;
        wh.x = pk(hh[0], hh[1]); wh.y = pk(hh[2], hh[3]);
        wh.z = pk(hh[4], hh[5]); wh.w = pk(hh[6], hh[7]);
        wmv.x = pk(mm[0], mm[1]); wmv.y = pk(mm[2], mm[3]);
        wmv.z = pk(mm[4], mm[5]); wmv.w = pk(mm[6], mm[7]);
        u16* dst = tb + kot * 2048 + m * 8;
        *(uint4*)dst          = wh;    // plane 0 (hi)
        *(uint4*)(dst + 8192) = wmv;   // plane 1 (mid)
    }
}

// ---- fused 3-product split-bf16 MFMA GEMM ----
// block: 512 threads (8 waves, 4m x 2n), M-chunk = 256, N-tile = 128, K-step 32, double-buffered
template<bool BN_IN, bool STORE, bool MAXMIN>
__global__ __launch_bounds__(512, 2)
void gemm3p(const u16* __restrict__ Wimg, int KT, int Kact, int M_,
            const float* __restrict__ bias,
            const float* __restrict__ X,            // [NB][Kact][4096] fp32
            const float2* __restrict__ ash,
            float* __restrict__ Y,
            float* __restrict__ psum, float* __restrict__ psq,
            float* __restrict__ pmax, float* __restrict__ pmin)
{
    __shared__ __align__(16) u16 As_[2 * 16384];   // [buf][plane 2][kot 4][m 256][8k]
    __shared__ __align__(16) u16 Bs_[2 * 8192];    // [buf][plane 2][kot 4][n 128][8k]

    const int tid = threadIdx.x;
    const int lane = tid & 63, wid = tid >> 6;
    const int l15 = lane & 15, l4 = lane >> 4;
    const int wm = wid >> 1, wn = wid & 1;
    const int nt = blockIdx.x, mtb = blockIdx.y, b = blockIdx.z;
    const int m0 = mtb * 256, n0 = nt * 128;
    const int nb = tid & 127, kob = tid >> 7;

    f32x4 acc[4][4];
#pragma unroll
    for (int i = 0; i < 4; ++i)
#pragma unroll
        for (int j = 0; j < 4; ++j) acc[i][j] = (f32x4){0.f, 0.f, 0.f, 0.f};

    const u16* wtile = Wimg + ((size_t)mtb * KT << 14);

    // invariant offsets (u16 units)
    const int afo = l4 * 2048 + (wm * 64 + l15) * 8;   // + mf*128, + plane*8192
    const int bfo = l4 * 1024 + (wn * 64 + l15) * 8;   // + nf*128, + plane*4096
    const int bwo = kob * 1024 + nb * 8;               // staging write

    float xr[8]; float2 ar[8];

#define STAGE_A(kt, buf)                                                          \
    {                                                                             \
        const u16* g_ = wtile + ((size_t)(kt) << 14);                             \
        u16* l_ = As_ + ((buf) << 14);                                            \
        _Pragma("unroll")                                                         \
        for (int i_ = 0; i_ < 4; ++i_)                                            \
            gload_lds16(g_ + wid * 2048 + i_ * 512 + lane * 8,                    \
                        l_ + wid * 2048 + i_ * 512);                              \
    }

#define READ_B(kt)                                                                \
    {                                                                             \
        const int kb_ = (kt) * 32 + kob * 8;                                      \
        const float* src_ = X + ((size_t)b * Kact + kb_) * NPTS + n0 + nb;        \
        _Pragma("unroll")                                                         \
        for (int j_ = 0; j_ < 8; ++j_) {                                          \
            const int k_ = kb_ + j_;                                              \
            xr[j_] = (k_ < Kact) ? src_[(size_t)j_ * NPTS] : 0.f;                 \
            if (BN_IN) ar[j_] = ash[(k_ < Kact) ? k_ : 0];                        \
        }                                                                         \
    }

#define WRITE_B(buf)                                                              \
    {                                                                             \
        u32 hh_[8], mm_[8];                                                       \
        _Pragma("unroll")                                                         \
        for (int j_ = 0; j_ < 8; ++j_) {                                          \
            float x_ = xr[j_];                                                    \
            if (BN_IN) x_ = fmaxf(fmaf(ar[j_].x, x_, ar[j_].y), 0.f);             \
            const u32 u_ = __float_as_uint(x_);                                   \
            const u32 uh_ = u_ + 0x8000u;                                         \
            const float r1_ = x_ - __uint_as_float(uh_ & 0xFFFF0000u);            \
            hh_[j_] = uh_;                                                        \
            mm_[j_] = __float_as_uint(r1_) + 0x8000u;                             \
        }                                                                         \
        uint4 wh_, wm_;                                                           \
        wh_.x = pk(hh_[0], hh_[1]); wh_.y = pk(hh_[2], hh_[3]);                   \
        wh_.z = pk(hh_[4], hh_[5]); wh_.w = pk(hh_[6], hh_[7]);                   \
        wm_.x = pk(mm_[0], mm_[1]); wm_.y = pk(mm_[2], mm_[3]);                   \
        wm_.z = pk(mm_[4], mm_[5]); wm_.w = pk(mm_[6], mm_[7]);                   \
        u16* d_ = Bs_ + ((buf) << 13) + bwo;                                      \
        *(uint4*)d_          = wh_;                                               \
        *(uint4*)(d_ + 4096) = wm_;                                               \
    }

#define COMPUTE(buf)                                                              \
    {                                                                             \
        const u16* A_ = As_ + ((buf) << 14);                                      \
        const u16* B_ = Bs_ + ((buf) << 13);                                      \
        short8 ah_[4], am_[4];                                                    \
        _Pragma("unroll")                                                         \
        for (int mf_ = 0; mf_ < 4; ++mf_) {                                       \
            ah_[mf_] = *(const short8*)(A_ + afo + mf_ * 128);                    \
            am_[mf_] = *(const short8*)(A_ + 8192 + afo + mf_ * 128);             \
        }                                                                         \
        _Pragma("unroll")                                                         \
        for (int nf_ = 0; nf_ < 4; ++nf_) {                                       \
            const short8 bh_ = *(const short8*)(B_ + bfo + nf_ * 128);            \
            const short8 bm_ = *(const short8*)(B_ + 4096 + bfo + nf_ * 128);     \
            _Pragma("unroll")                                                     \
            for (int mf_ = 0; mf_ < 4; ++mf_)                                     \
                acc[mf_][nf_] = __builtin_amdgcn_mfma_f32_16x16x32_bf16(          \
                    ah_[mf_], bh_, acc[mf_][nf_], 0, 0, 0);                       \
            _Pragma("unroll")                                                     \
            for (int mf_ = 0; mf_ < 4; ++mf_)                                     \
                acc[mf_][nf_] = __builtin_amdgcn_mfma_f32_16x16x32_bf16(          \
                    ah_[mf_], bm_, acc[mf_][nf_], 0, 0, 0);                       \
            _Pragma("unroll")                                                     \
            for (int mf_ = 0; mf_ < 4; ++mf_)                                     \
                acc[mf_][nf_] = __builtin_amdgcn_mfma_f32_16x16x32_bf16(          \
                    am_[mf_], bh_, acc[mf_][nf_], 0, 0, 0);                       \
        }                                                                         \
    }

    // prologue: stage kt=0 into buf 0
    STAGE_A(0, 0);
    READ_B(0);
    WRITE_B(0);
    __syncthreads();

    int cur = 0;
    for (int kt = 0; kt < KT; ++kt) {
        const int nx = kt + 1;
        if (nx < KT) {
            STAGE_A(nx, cur ^ 1);
            READ_B(nx);
        }
        COMPUTE(cur);
        if (nx < KT) WRITE_B(cur ^ 1);
        __syncthreads();
        cur ^= 1;
    }

    // ---- epilogue: bias, stats partials, optional store / max-min partials ----
#pragma unroll
    for (int mf = 0; mf < 4; ++mf) {
#pragma unroll
        for (int r = 0; r < 4; ++r) {
            const int m = m0 + wm * 64 + mf * 16 + l4 * 4 + r;
            const float bvv = bias[m];
            float vs[4];
            float rs = 0.f, rq = 0.f;
#pragma unroll
            for (int nf = 0; nf < 4; ++nf) {
                const float v = acc[mf][nf][r] + bvv;
                vs[nf] = v; rs += v; rq = fmaf(v, v, rq);
            }
            float mx = 0.f, mn = 0.f;
            if (MAXMIN) {
                mx = fmaxf(fmaxf(vs[0], vs[1]), fmaxf(vs[2], vs[3]));
                mn = fminf(fminf(vs[0], vs[1]), fminf(vs[2], vs[3]));
            }
            if (STORE) {
#pragma unroll
                for (int nf = 0; nf < 4; ++nf)
                    Y[((size_t)b * M_ + m) * NPTS + n0 + wn * 64 + nf * 16 + l15] = vs[nf];
            }
#pragma unroll
            for (int s = 1; s < 16; s <<= 1) {
                rs += __shfl_xor(rs, s);
                rq += __shfl_xor(rq, s);
                if (MAXMIN) {
                    mx = fmaxf(mx, __shfl_xor(mx, s));
                    mn = fminf(mn, __shfl_xor(mn, s));
                }
            }
            if (l15 == 0) {
                const int slot = (b * 32 + nt) * 2 + wn;
                psum[(size_t)slot * M_ + m] = rs;
                psq[(size_t)slot * M_ + m]  = rq;
                if (MAXMIN) {
                    pmax[((size_t)b * M_ + m) * 64 + nt * 2 + wn] = mx;
                    pmin[((size_t)b * M_ + m) * 64 + nt * 2 + wn] = mn;
                }
            }
        }
    }
#undef STAGE_A
#undef READ_B
#undef WRITE_B
#undef COMPUTE
}

// ---- per-channel stats (1024 slots) -> BN scale/shift (+ packed float2) ----
__global__ __launch_bounds__(256) void stats_k(const float* __restrict__ psum, const float* __restrict__ psq,
                                               int M_,
                                               const float* __restrict__ g, const float* __restrict__ be,
                                               float* __restrict__ a_out, float* __restrict__ sh_out,
                                               float2* __restrict__ ash)
{
    __shared__ double ds[4][64];
    __shared__ double dq[4][64];
    const int mloc = threadIdx.x & 63, q = threadIdx.x >> 6;
    const int m = blockIdx.x * 64 + mloc;
    double s = 0.0, sq = 0.0;
    for (int sl = q * 256; sl < (q + 1) * 256; ++sl) {
        s  += (double)psum[(size_t)sl * M_ + m];
        sq += (double)psq[(size_t)sl * M_ + m];
    }
    ds[q][mloc] = s; dq[q][mloc] = sq;
    __syncthreads();
    if (threadIdx.x < 64) {
        const double S = ds[0][mloc] + ds[1][mloc] + ds[2][mloc] + ds[3][mloc];
        const double Q = dq[0][mloc] + dq[1][mloc] + dq[2][mloc] + dq[3][mloc];
        const double cnt = (double)NB * (double)NPTS;
        double mean = S / cnt;
        double var  = Q / cnt - mean * mean;
        if (var < 0.0) var = 0.0;
        const double a = (double)g[m] / sqrt(var + 1e-5);
        const float af = (float)a;
        const float sf = (float)((double)be[m] - a * mean);
        a_out[m]  = af;
        sh_out[m] = sf;
        ash[m] = make_float2(af, sf);
    }
}

// ---- final: fused L3-stats, pool-select, BN-apply+ReLU, BN1d over batch ----
__global__ __launch_bounds__(256) void final_k(const float* __restrict__ psum, const float* __restrict__ psq,
                                               const float* __restrict__ g3, const float* __restrict__ be3,
                                               const float* __restrict__ pmax, const float* __restrict__ pmin,
                                               const float* __restrict__ g4, const float* __restrict__ be4,
                                               float* __restrict__ out)
{
    const int c = blockIdx.x * 256 + threadIdx.x;
    if (c >= 1024) return;
    double S = 0.0, Q = 0.0;
    for (int sl = 0; sl < 1024; ++sl) {
        S += (double)psum[(size_t)sl * 1024 + c];
        Q += (double)psq[(size_t)sl * 1024 + c];
    }
    const double cnt = (double)NB * (double)NPTS;
    double mean3 = S / cnt;
    double var3  = Q / cnt - mean3 * mean3;
    if (var3 < 0.0) var3 = 0.0;
    const double a3 = (double)g3[c] / sqrt(var3 + 1e-5);
    const float a = (float)a3;
    const float sh = (float)((double)be3[c] - a3 * mean3);

    float h[NB];
    float s = 0.f;
    for (int b = 0; b < NB; ++b) {
        float mxv = -FLT_BIG, mnv = FLT_BIG;
        const float* pxr = pmax + ((size_t)b * 1024 + c) * 64;
        const float* pnr = pmin + ((size_t)b * 1024 + c) * 64;
        for (int q = 0; q < 64; ++q) {
            mxv = fmaxf(mxv, pxr[q]);
            mnv = fminf(mnv, pnr[q]);
        }
        const float v = (a >= 0.f) ? fmaf(a, mxv, sh) : fmaf(a, mnv, sh);
        h[b] = fmaxf(v, 0.f);
        s += h[b];
    }
    const float mean = s * (1.f / NB);
    float var = 0.f;
    for (int b = 0; b < NB; ++b) { const float d = h[b] - mean; var = fmaf(d, d, var); }
    var *= (1.f / NB);
    const double ai = (double)g4[c] / sqrt((double)var + 1e-5);
    for (int b = 0; b < NB; ++b)
        out[b * 1024 + c] = (float)(ai * ((double)h[b] - (double)mean) + (double)be4[c]);
}

extern "C" void kernel_launch(void* const* d_in, const int* in_sizes, int n_in,
                              void* d_out, int out_size, void* d_ws, size_t ws_size,
                              hipStream_t stream) {
    const float* xyz = (const float*)d_in[0];
    const float* W1  = (const float*)d_in[1];
    const float* b1  = (const float*)d_in[2];
    const float* g1  = (const float*)d_in[3];
    const float* be1 = (const float*)d_in[4];
    const float* W2  = (const float*)d_in[5];
    const float* b2  = (const float*)d_in[6];
    const float* g2  = (const float*)d_in[7];
    const float* be2 = (const float*)d_in[8];
    const float* W3  = (const float*)d_in[9];
    const float* b3  = (const float*)d_in[10];
    const float* g3  = (const float*)d_in[11];
    const float* be3 = (const float*)d_in[12];
    const float* g4  = (const float*)d_in[13];
    const float* be4 = (const float*)d_in[14];

    float* ws = (float*)d_ws;
    float* y1  = ws + OFF_Y1;
    float* y2  = ws + OFF_Y2;
    u16*   w1i = (u16*)(ws + OFF_W1I);
    u16*   w2i = (u16*)(ws + OFF_W2I);
    u16*   w3i = (u16*)(ws + OFF_W3I);
    float* ps  = ws + OFF_PS;
    float* pq  = ws + OFF_PQ;
    float* pmx = ws + OFF_PMX;
    float* pmn = ws + OFF_PMN;
    float* ac  = ws + OFF_AC;
    float* shc = ws + OFF_SHC;
    float2* ash = (float2*)(ws + OFF_ASH);
    float* out = (float*)d_out;

    // W images: L1 21 tiles, L2 16, L3 64
    prep_w<<<101, 256, 0, stream>>>(W1, W2, W3, w1i, w2i, w3i);

    // L1: y1 = W1 @ xyz + b1 (store + stats). grid (nt=32, mtb=1, b=16)
    gemm3p<false, true, false><<<dim3(32, 1, 16), 512, 0, stream>>>(
        w1i, 21, 643, 256, b1, xyz, nullptr,
        y1, ps, pq, nullptr, nullptr);
    stats_k<<<4, 256, 0, stream>>>(ps, pq, 256, g1, be1, ac, shc, ash);

    // L2: y2 = W2 @ relu(bn(y1)) + b2 (store + stats). grid (32, 2, 16)
    gemm3p<true, true, false><<<dim3(32, 2, 16), 512, 0, stream>>>(
        w2i, 8, 256, 512, b2, y1, ash,
        y2, ps, pq, nullptr, nullptr);
    stats_k<<<8, 256, 0, stream>>>(ps, pq, 512, g2, be2, ac, shc, ash);

    // L3: stats + per-(b,m) max/min partials (no store). grid (32, 4, 16)
    gemm3p<true, false, true><<<dim3(32, 4, 16), 512, 0, stream>>>(
        w3i, 16, 512, 1024, b3, y2, ash,
        nullptr, ps, pq, pmx, pmn);

    // fused L3-stats + pool-select + final BN1d
    final_k<<<4, 256, 0, stream>>>(ps, pq, g3, be3, pmx, pmn, g4, be4, out);
}